// Round 1
// baseline (63.399 us; speedup 1.0000x reference)
//
#include <hip/hip_runtime.h>
#include <math.h>

#define VOCAB 1000000
#define D 64
#define BATCH 16384
#define SEQ 50

// One 64-lane wave per batch row.
// Phase A: lane l (<50) computes score[l] = dot(emb[idx[l]], w) + bias  (per-lane row read)
// Phase B: masked softmax across lanes via shfl_xor butterflies
// Phase C: lane d accumulates pooled[d] = sum_l attn[l] * emb[idx[l]][d]
//          (uniform SGPR row base per l via readlane -> coalesced 256B loads)
__global__ __launch_bounds__(256) void attn_pool_kernel(
    const int* __restrict__ idx,
    const float* __restrict__ emb,
    const float* __restrict__ w,     // [D]
    const float* __restrict__ bias,  // [1]
    float* __restrict__ out)         // [BATCH][D]
{
    const int wave = (int)((blockIdx.x * blockDim.x + threadIdx.x) >> 6);
    const int lane = (int)(threadIdx.x & 63);
    if (wave >= BATCH) return;

    // ---- load idx (lane l holds idx[wave][l]) ----
    int my_idx = 0;
    if (lane < SEQ) my_idx = idx[wave * SEQ + lane];

    bool valid = (lane < SEQ) && (my_idx != 0);
    unsigned long long ballot = __ballot(valid);
    if (ballot == 0ULL && lane == 0) valid = true;  // all-pad row: force l=0

    // ---- Phase A: per-lane dot product ----
    float score = 0.0f;
    if (lane < SEQ) {
        const float4* rp = reinterpret_cast<const float4*>(emb + (size_t)my_idx * D);
        const float4* wp = reinterpret_cast<const float4*>(w);
        float acc = 0.0f;
        #pragma unroll
        for (int k = 0; k < D / 4; ++k) {
            float4 e = rp[k];
            float4 ww = wp[k];
            acc += e.x * ww.x + e.y * ww.y + e.z * ww.z + e.w * ww.w;
        }
        score = acc + bias[0];
    }

    // ---- Phase B: masked softmax across the wave ----
    float ms = valid ? score : -INFINITY;
    float m = ms;
    #pragma unroll
    for (int s = 1; s < 64; s <<= 1) m = fmaxf(m, __shfl_xor(m, s));

    float p = valid ? __expf(score - m) : 0.0f;
    float sum = p;
    #pragma unroll
    for (int s = 1; s < 64; s <<= 1) sum += __shfl_xor(sum, s);

    float attn = p / sum;  // sum >= exp(0) = 1 for the max valid lane

    // ---- Phase C: weighted sum, lane = output dim d ----
    float pooled = 0.0f;
    #pragma unroll
    for (int l = 0; l < SEQ; ++l) {
        float a = __uint_as_float(
            __builtin_amdgcn_readlane(__float_as_uint(attn), l));
        int il = __builtin_amdgcn_readlane(my_idx, l);
        pooled += a * emb[(size_t)il * D + lane];
    }

    out[wave * D + lane] = pooled;
}

extern "C" void kernel_launch(void* const* d_in, const int* in_sizes, int n_in,
                              void* d_out, int out_size, void* d_ws, size_t ws_size,
                              hipStream_t stream) {
    const int*   idx  = (const int*)d_in[0];
    const float* emb  = (const float*)d_in[1];
    const float* w    = (const float*)d_in[2];
    const float* bias = (const float*)d_in[3];
    float* out = (float*)d_out;

    const int threads = 256;                       // 4 waves per block
    const int waves_per_block = threads / 64;
    const int blocks = BATCH / waves_per_block;    // 4096
    attn_pool_kernel<<<blocks, threads, 0, stream>>>(idx, emb, w, bias, out);
}

// Round 2
// 37.507 us; speedup vs baseline: 1.6903x; 1.6903x over previous
//
#include <hip/hip_runtime.h>
#include <math.h>

#define VOCAB 1000000
#define D 64
#define BATCH 16384
#define SEQ 50

// One 64-lane wave per batch row. Single pass over embedding rows:
//  Phase L: 50 fully-coalesced 256B row loads (lane = dim), rows stay in VGPRs e[50]
//  Phase S: c[l] = e[l]*w[lane]; all-to-all butterfly reduce puts score[l] on lane l
//  Phase M: masked softmax across lanes (shfl_xor butterflies)
//  Phase P: pooled[lane] = sum_l readlane(attn,l) * e[l]   (pure register FMAs)
__global__ __launch_bounds__(256) void attn_pool_kernel(
    const int* __restrict__ idx,
    const float* __restrict__ emb,
    const float* __restrict__ w,     // [D]
    const float* __restrict__ bias,  // [1]
    float* __restrict__ out)         // [BATCH][D]
{
    const int wave = (int)((blockIdx.x * blockDim.x + threadIdx.x) >> 6);
    const int lane = (int)(threadIdx.x & 63);
    if (wave >= BATCH) return;

    // lane l (<50) holds idx[wave][l]
    int my_idx = 0;
    if (lane < SEQ) my_idx = idx[wave * SEQ + lane];

    bool valid = (lane < SEQ) && (my_idx != 0);
    unsigned long long ballot = __ballot(valid);
    if (ballot == 0ULL && lane == 0) valid = true;  // all-pad row: force l=0

    const float wl = w[lane];

    // ---- Phase L: coalesced row loads, rows resident in registers ----
    float e[SEQ];
    #pragma unroll
    for (int l = 0; l < SEQ; ++l) {
        int il = __builtin_amdgcn_readlane(my_idx, l);   // SGPR row index
        e[l] = emb[(size_t)il * D + lane];               // 256B coalesced
    }

    // ---- Phase S: per-lane partials, then all-to-all butterfly reduce.
    // red[l] starts as c[l] = e[l][lane] * w[lane]; arrays 50..63 are zero and
    // are pruned (guards inject 0.0f). After 6 steps lane l holds
    // score_raw[l] = sum_d e[l][d]*w[d].
    float red[SEQ];
    #pragma unroll
    for (int l = 0; l < SEQ; ++l) red[l] = e[l] * wl;

    static const int LENS[7] = {50, 25, 13, 7, 4, 2, 1};
    #pragma unroll
    for (int step = 0; step < 6; ++step) {
        const int m = 1 << step;
        const int len = LENS[step];
        const int npair = LENS[step + 1];
        const bool up = (lane & m) != 0;
        #pragma unroll
        for (int j = 0; j < npair; ++j) {
            float a = red[2 * j];
            float b = (2 * j + 1 < len) ? red[2 * j + 1] : 0.0f;
            float send = up ? a : b;            // send partner's kept index
            float recv = __shfl_xor(send, m);
            red[j] = (up ? b : a) + recv;       // keep own index, add partner's copy
        }
    }
    float score = red[0] + bias[0];   // lane l holds score[l]; lanes >=50 hold bias (masked)

    // ---- Phase M: masked softmax across the wave ----
    float ms = valid ? score : -INFINITY;
    float m = ms;
    #pragma unroll
    for (int s = 1; s < 64; s <<= 1) m = fmaxf(m, __shfl_xor(m, s));

    float p = valid ? __expf(score - m) : 0.0f;
    float sum = p;
    #pragma unroll
    for (int s = 1; s < 64; s <<= 1) sum += __shfl_xor(sum, s);

    float attn = p / sum;

    // ---- Phase P: weighted sum over register-resident rows ----
    float pooled = 0.0f;
    #pragma unroll
    for (int l = 0; l < SEQ; ++l) {
        float a = __uint_as_float(
            __builtin_amdgcn_readlane(__float_as_uint(attn), l));
        pooled = fmaf(a, e[l], pooled);
    }

    out[wave * D + lane] = pooled;
}

extern "C" void kernel_launch(void* const* d_in, const int* in_sizes, int n_in,
                              void* d_out, int out_size, void* d_ws, size_t ws_size,
                              hipStream_t stream) {
    const int*   idx  = (const int*)d_in[0];
    const float* emb  = (const float*)d_in[1];
    const float* w    = (const float*)d_in[2];
    const float* bias = (const float*)d_in[3];
    float* out = (float*)d_out;

    const int threads = 256;                       // 4 waves per block
    const int waves_per_block = threads / 64;
    const int blocks = BATCH / waves_per_block;    // 4096
    attn_pool_kernel<<<blocks, threads, 0, stream>>>(idx, emb, w, bias, out);
}